// Round 13
// baseline (430.749 us; speedup 1.0000x reference)
//
#include <hip/hip_runtime.h>
#include <math.h>

// MACE-like block on gfx950. CSR-sorted edge aggregation + f16 MFMA radial
// GEMM fused with message/scatter; node transforms in the measured-best R5
// access pattern.
//
// R13 = R12 (measured 417 us) + fagg2 column-split:
//   stage-2 lane c only reads R cols c*6..c*6+5, so the 384-col tile is
//   processed in two 192-col halves reusing one 6 KB LDS slice per wave.
//   LDS/block 48 -> 24 KB, 3 -> 6 blocks/CU (12 -> 24 waves/CU) to cover
//   the up1-gather latency that dominates fagg2 (occupancy was 27%).
// Sizes: N=10000 nodes, E=160000 edges, C=64, 16 sph, S=10 species.

#define WAVE_SZ 64

typedef _Float16 half8 __attribute__((ext_vector_type(8)));
typedef float f32x4 __attribute__((ext_vector_type(4)));

__device__ __forceinline__ float silu_f(float x) { return x / (1.0f + expf(-x)); }

__device__ __forceinline__ float reduce64(float v) {
#pragma unroll
  for (int off = 32; off > 0; off >>= 1) v += __shfl_xor(v, off, WAVE_SZ);
  return v;
}

__device__ __forceinline__ void compute_Y(float x, float y, float z, float* Y) {
  float x2 = x * x, y2 = y * y, z2 = z * z;
  Y[0] = 1.0f;
  Y[1] = 1.7320508f * x;
  Y[2] = 1.7320508f * y;
  Y[3] = 1.7320508f * z;
  Y[4] = 3.8729833f * x * y;
  Y[5] = 3.8729833f * y * z;
  Y[6] = 1.118034f * (3.0f * z2 - 1.0f);
  Y[7] = 3.8729833f * x * z;
  Y[8] = 1.9364917f * (x2 - y2);
  Y[9] = 2.09165f * y * (3.0f * x2 - y2);
  Y[10] = 10.246951f * x * y * z;
  Y[11] = 1.6201852f * y * (5.0f * z2 - 1.0f);
  Y[12] = 1.3228757f * z * (5.0f * z2 - 3.0f);
  Y[13] = 1.6201852f * x * (5.0f * z2 - 1.0f);
  Y[14] = 5.1234753f * z * (x2 - y2);
  Y[15] = 2.09165f * x * (x2 - 3.0f * y2);
}

__device__ __forceinline__ void compute_rb(float r, float inv_r, float* rb) {
  float t = fminf(r * 0.2f, 1.0f);
  float t2 = t * t;
  float t5 = t2 * t2 * t;
  float env = 1.0f + t5 * (-21.0f + t * (35.0f - 15.0f * t));
  float th = 0.62831853f * r;  // pi * r / 5
  float s1 = sinf(th), c1 = cosf(th);
  float c2 = 2.0f * c1;
  float sprev = 0.0f, scur = s1;
  float coef = 0.63245553f * inv_r * env;
#pragma unroll
  for (int k = 0; k < 8; k++) {
    rb[k] = coef * scur;
    float snxt = c2 * scur - sprev;
    sprev = scur;
    scur = snxt;
  }
}

// ------------------------------------------------------------- CSR build (edges)
__global__ __launch_bounds__(256) void k_hist(const int* __restrict__ receivers,
                                              int* __restrict__ cnt, int E) {
  int e = blockIdx.x * 256 + threadIdx.x;
  if (e < E) atomicAdd(&cnt[receivers[e]], 1);
}

__global__ __launch_bounds__(256) void k_scan(const int* __restrict__ deg,
                                              int* __restrict__ row_start,
                                              int* __restrict__ cursor, int N) {
  __shared__ int part[256];
  int t = threadIdx.x;
  int K = (N + 255) / 256;
  int lo = t * K, hi = min(lo + K, N);
  int s = 0;
  for (int i = lo; i < hi; i++) s += deg[i];
  part[t] = s;
  __syncthreads();
  for (int d = 1; d < 256; d <<= 1) {
    int v = (t >= d) ? part[t - d] : 0;
    __syncthreads();
    part[t] += v;
    __syncthreads();
  }
  int run = (t == 0) ? 0 : part[t - 1];
  for (int i = lo; i < hi; i++) {
    int di = deg[i];  // deg aliases cursor; must read before overwrite
    row_start[i] = run;
    cursor[i] = run;
    run += di;
  }
  if (t == 255) row_start[N] = part[255];
}

__global__ __launch_bounds__(256) void k_scatter(const int* __restrict__ receivers,
                                                 const int* __restrict__ senders,
                                                 int* __restrict__ cursor,
                                                 int* __restrict__ perm,
                                                 int* __restrict__ rsort,
                                                 int* __restrict__ ssort, int E) {
  int e = blockIdx.x * 256 + threadIdx.x;
  if (e < E) {
    int r = receivers[e];
    int pos = atomicAdd(&cursor[r], 1);
    perm[pos] = e;
    rsort[pos] = r;
    ssort[pos] = senders[e];
  }
}

// ------------------------------------------------------------- pack rw2 -> f16 B^T
// b1t[n][k] with n = c*2+j, j in {0,1}            (128 x 64 halves)
// b2t[n][k] with n = c*6+j, cols {0,1,2,3,5,9}    (384 x 64 halves)
__global__ __launch_bounds__(256) void k_pack(const float* __restrict__ rw2,
                                              _Float16* __restrict__ b1t,
                                              _Float16* __restrict__ b2t) {
  int idx = blockIdx.x * 256 + threadIdx.x;
  if (idx < 8192) {
    int n = idx >> 6, k = idx & 63;
    int c = n >> 1, j = n & 1;
    b1t[idx] = (_Float16)rw2[k * 768 + c * 12 + j];
  } else if (idx < 32768) {
    int i2 = idx - 8192;
    int n = i2 >> 6, k = i2 & 63;
    int c = n / 6, j = n - c * 6;
    int col = (j < 4) ? j : ((j == 4) ? 5 : 9);
    b2t[i2] = (_Float16)rw2[49152 + k * 768 + c * 12 + col];
  }
}

// ------------------------------------------------------------- up0
__global__ __launch_bounds__(256) void k_up0(const float* __restrict__ embed,
                                             const float* __restrict__ lu0,
                                             const int* __restrict__ species,
                                             float* __restrict__ up0, int N) {
  int wave = threadIdx.x >> 6, lane = threadIdx.x & 63;
  int n = (blockIdx.x << 2) + wave;
  if (n >= N) return;
  int sp = species[n];
  const float* er = embed + sp * 64;
  float acc = 0.0f;
#pragma unroll 8
  for (int c = 0; c < 64; c++) acc += er[c] * lu0[c * 64 + lane];
  up0[(size_t)n * 64 + lane] = acc;
}

// ------------------------------------------------------------- geometry (sorted)
__global__ __launch_bounds__(256) void k_geom(const float* __restrict__ ev,
                                              const float* __restrict__ rw1,
                                              const int* __restrict__ perm,
                                              _Float16* __restrict__ hid0,
                                              _Float16* __restrict__ hid1,
                                              float* __restrict__ Ysort,
                                              int* __restrict__ rsort,
                                              int* __restrict__ ssort,
                                              int E, int EPAD) {
  int wave = threadIdx.x >> 6, lane = threadIdx.x & 63;
  int j = blockIdx.x * 4 + wave;
  if (j >= EPAD) return;
  if (j >= E) {
    hid0[(size_t)j * 64 + lane] = (_Float16)0.0f;
    hid1[(size_t)j * 64 + lane] = (_Float16)0.0f;
    if (lane == 0) { rsort[j] = -1; ssort[j] = 0; }
    if (lane < 16) Ysort[(size_t)j * 16 + lane] = 0.0f;
    return;
  }
  int e = perm[j];
  float vx = ev[e * 3 + 0], vy = ev[e * 3 + 1], vz = ev[e * 3 + 2];
  float r = sqrtf(vx * vx + vy * vy + vz * vz);
  float inv_r = 1.0f / (r + 1e-8f);
  float Y[16];
  compute_Y(vx * inv_r, vy * inv_r, vz * inv_r, Y);
  float rb[8];
  compute_rb(r, inv_r, rb);

  float h0 = 0.0f, h1 = 0.0f;
#pragma unroll
  for (int k = 0; k < 8; k++) {
    h0 += rb[k] * rw1[k * 64 + lane];
    h1 += rb[k] * rw1[512 + k * 64 + lane];
  }
  hid0[(size_t)j * 64 + lane] = (_Float16)silu_f(h0);
  hid1[(size_t)j * 64 + lane] = (_Float16)silu_f(h1);

  // lane m (m < 16) stores Y[m]; static selects avoid scratch spill
  float yv = Y[0];
#pragma unroll
  for (int m = 1; m < 16; m++) yv = (lane == m) ? Y[m] : yv;
  if (lane < 16) Ysort[(size_t)j * 16 + lane] = yv;
}

// ------------------------------------------------------------- fagg pass 1 (pruned)
// Only m < 4 of the aggregate is live downstream -> R cols {0,1}, 128-col
// MFMA tile, 4 accumulators, 4 atomics per receiver flush.
__global__ __launch_bounds__(256) void k_fagg1(const _Float16* __restrict__ hid,
                                               const _Float16* __restrict__ bt,
                                               const float* __restrict__ Ysort,
                                               const float* __restrict__ up0,
                                               const int* __restrict__ ssort,
                                               const int* __restrict__ rsort,
                                               float* __restrict__ agg1c, int E) {
  __shared__ _Float16 __attribute__((aligned(16))) lds[4][16 * 128];  // 16 KB
  int wave = threadIdx.x >> 6, lane = threadIdx.x & 63;
  int q = lane >> 4, mr = lane & 15;
  _Float16* L = lds[wave];
  int j0 = __builtin_amdgcn_readfirstlane((blockIdx.x * 4 + wave) * 16);

  int rs[16], ss[16];
#pragma unroll
  for (int t = 0; t < 16; t++) {
    rs[t] = rsort[j0 + t];
    ss[t] = ssort[j0 + t];
  }
  float hsv[16];
#pragma unroll
  for (int t = 0; t < 16; t++) hsv[t] = up0[((size_t)ss[t] << 6) + lane];

  const half8* Ap = (const half8*)(hid + (size_t)(j0 + mr) * 64 + q * 8);
  half8 a0 = Ap[0];
  half8 a1 = Ap[4];
  const _Float16* bp = bt + (size_t)mr * 64 + q * 8;
#pragma unroll
  for (int T = 0; T < 8; T++) {
    half8 b0 = *(const half8*)(bp + T * 1024);
    half8 b1 = *(const half8*)(bp + T * 1024 + 32);
    f32x4 acc = {0.f, 0.f, 0.f, 0.f};
    acc = __builtin_amdgcn_mfma_f32_16x16x32_f16(a0, b0, acc, 0, 0, 0);
    acc = __builtin_amdgcn_mfma_f32_16x16x32_f16(a1, b1, acc, 0, 0, 0);
#pragma unroll
    for (int r = 0; r < 4; r++)
      L[(q * 4 + r) * 128 + T * 16 + mr] = (_Float16)acc[r];
  }

  float accm[4] = {0.f, 0.f, 0.f, 0.f};
  int cur_r = (j0 < E) ? rs[0] : -1;

#pragma unroll
  for (int t = 0; t < 16; t++) {
    int j = j0 + t;
    bool ok = (j < E);
    int rr = ok ? rs[t] : -2;
    if (rr != cur_r) {  // wave-uniform branch
      if (cur_r >= 0) {
        float* base = agg1c + ((size_t)cur_r << 8) + lane;
#pragma unroll
        for (int m = 0; m < 4; m++) atomicAdd(base + (m << 6), accm[m]);
      }
#pragma unroll
      for (int m = 0; m < 4; m++) accm[m] = 0.0f;
      cur_r = rr;
    }
    if (ok) {
      float hs0 = hsv[t];
      const _Float16* Rr = L + t * 128 + lane * 2;
      float p0 = (float)Rr[0] * hs0;
      float p1 = (float)Rr[1] * hs0;
      float4 Ya = *(const float4*)(Ysort + (size_t)j * 16);  // wave-uniform
      accm[0] += p0;
      accm[1] += p1 * Ya.y;
      accm[2] += p1 * Ya.z;
      accm[3] += p1 * Ya.w;
    }
  }
  if (cur_r >= 0) {
    float* base = agg1c + ((size_t)cur_r << 8) + lane;
#pragma unroll
    for (int m = 0; m < 4; m++) atomicAdd(base + (m << 6), accm[m]);
  }
}

// ------------------------------------------------------------- fagg pass 2
// Column-split: lane c consumes only R cols c*6..c*6+5, so process the 384
// cols as two 192-col halves through one 6 KB LDS slice per wave. Halves
// serve lanes 0..31 and 32..63 respectively; receiver-scan state is
// wave-uniform so the flush logic simply runs once per half with the
// corresponding lanes active.
__global__ __launch_bounds__(256) void k_fagg2(const _Float16* __restrict__ hid,
                                               const _Float16* __restrict__ bt,
                                               const float* __restrict__ Ysort,
                                               const float* __restrict__ up1,
                                               const int* __restrict__ ssort,
                                               const int* __restrict__ rsort,
                                               float* __restrict__ agg, int E) {
  __shared__ _Float16 __attribute__((aligned(16))) lds[4][16 * 192];  // 24 KB
  int wave = threadIdx.x >> 6, lane = threadIdx.x & 63;
  int q = lane >> 4, mr = lane & 15;
  _Float16* L = lds[wave];
  int j0 = __builtin_amdgcn_readfirstlane((blockIdx.x * 4 + wave) * 16);
  int half_id = lane >> 5;

  int rs[16], ss[16];
#pragma unroll
  for (int t = 0; t < 16; t++) {
    rs[t] = rsort[j0 + t];
    ss[t] = ssort[j0 + t];
  }
  float4 hv[16];
#pragma unroll
  for (int t = 0; t < 16; t++)
    hv[t] = *(const float4*)(up1 + ((size_t)ss[t] << 8) + lane * 4);

  const half8* Ap = (const half8*)(hid + (size_t)(j0 + mr) * 64 + q * 8);
  half8 a0 = Ap[0];
  half8 a1 = Ap[4];
  const _Float16* bp = bt + (size_t)mr * 64 + q * 8;

  float accm[16];
#pragma unroll
  for (int m = 0; m < 16; m++) accm[m] = 0.0f;

#pragma unroll
  for (int half = 0; half < 2; half++) {
    // MFMA: 12 tiles covering cols half*192 .. half*192+191
#pragma unroll
    for (int T = 0; T < 12; T++) {
      int Tg = half * 12 + T;
      half8 b0 = *(const half8*)(bp + Tg * 1024);
      half8 b1 = *(const half8*)(bp + Tg * 1024 + 32);
      f32x4 acc = {0.f, 0.f, 0.f, 0.f};
      acc = __builtin_amdgcn_mfma_f32_16x16x32_f16(a0, b0, acc, 0, 0, 0);
      acc = __builtin_amdgcn_mfma_f32_16x16x32_f16(a1, b1, acc, 0, 0, 0);
#pragma unroll
      for (int r = 0; r < 4; r++)
        L[(q * 4 + r) * 192 + T * 16 + mr] = (_Float16)acc[r];
    }

    // stage 2 for this half's lanes (same-wave DS ordering; no barrier)
    bool act = (half_id == half);
    int cur_r = (j0 < E) ? rs[0] : -1;
#pragma unroll
    for (int t = 0; t < 16; t++) {
      int j = j0 + t;
      bool ok = (j < E);
      int rr = ok ? rs[t] : -2;
      if (rr != cur_r) {  // wave-uniform branch
        if (cur_r >= 0) {
          float* base = agg + ((size_t)cur_r << 10) + lane;
          if (act) {
#pragma unroll
            for (int m = 0; m < 16; m++) atomicAdd(base + (m << 6), accm[m]);
          }
        }
#pragma unroll
        for (int m = 0; m < 16; m++) accm[m] = 0.0f;
        cur_r = rr;
      }
      if (ok && act) {
        float4 hs = hv[t];
        float hs0 = hs.x, hs1 = hs.y, hs2 = hs.z, hs3 = hs.w;
        const _Float16* Rr = L + t * 192 + (lane & 31) * 6;
        float R0 = (float)Rr[0], R1v = (float)Rr[1];
        float R2v = (float)Rr[2], R3v = (float)Rr[3];
        float c5 = (float)Rr[4], c9 = (float)Rr[5];
        float q0 = R0 * hs0, q1 = R1v * hs0, q2 = R2v * hs0, q3 = R3v * hs0;
        const float* Yj = Ysort + (size_t)j * 16;
        float4 Ya = *(const float4*)(Yj);
        float4 Yb = *(const float4*)(Yj + 4);
        float4 Yc = *(const float4*)(Yj + 8);
        float4 Yd = *(const float4*)(Yj + 12);
        accm[0] += q0 + c9 * (hs1 * Ya.y + hs2 * Ya.z + hs3 * Ya.w);
        accm[1] += q1 * Ya.y + c5 * hs1;
        accm[2] += q1 * Ya.z + c5 * hs2;
        accm[3] += q1 * Ya.w + c5 * hs3;
        accm[4] += q2 * Yb.x;
        accm[5] += q2 * Yb.y;
        accm[6] += q2 * Yb.z;
        accm[7] += q2 * Yb.w;
        accm[8] += q2 * Yc.x;
        accm[9] += q3 * Yc.y;
        accm[10] += q3 * Yc.z;
        accm[11] += q3 * Yc.w;
        accm[12] += q3 * Yd.x;
        accm[13] += q3 * Yd.y;
        accm[14] += q3 * Yd.z;
        accm[15] += q3 * Yd.w;
      }
    }
    if (cur_r >= 0 && act) {
      float* base = agg + ((size_t)cur_r << 10) + lane;
#pragma unroll
      for (int m = 0; m < 16; m++) atomicAdd(base + (m << 6), accm[m]);
    }
  }
}

// ------------------------------------------------------------- node kernel 1
// R5 structure, pruned to m < 4: stage A/B use l=0 (m=0) and l=1 (m=1..3).
__global__ __launch_bounds__(64) void k_node1(const float* __restrict__ agg1c,
                                              const float* __restrict__ ld0,
                                              const float* __restrict__ sel_w,
                                              const float* __restrict__ pw0,
                                              const float* __restrict__ res_w,
                                              const float* __restrict__ lu1,
                                              const float* __restrict__ read0,
                                              const int* __restrict__ species,
                                              float* __restrict__ out,
                                              float* __restrict__ res,
                                              float* __restrict__ up1, int N) {
  int n = blockIdx.x, d = threadIdx.x;
  int sp = species[n];
  __shared__ float sA[256], sB[256];

  const float* ag = agg1c + ((size_t)n << 8);
#pragma unroll
  for (int m = 0; m < 4; m++) sA[m * 64 + d] = ag[(m << 6) + d] * 0.0625f;
  __syncthreads();

  // stage A: fint = agg @ ld0[l]
  float fr[4] = {0.f, 0.f, 0.f, 0.f};
  {
    const float* W0 = ld0 + d;
    const float* W1 = ld0 + 4096 + d;
#pragma unroll 8
    for (int c = 0; c < 64; c++) {
      float w0 = W0[c * 64], w1 = W1[c * 64];
      fr[0] += sA[c] * w0;
      fr[1] += sA[64 + c] * w1;
      fr[2] += sA[128 + c] * w1;
      fr[3] += sA[192 + c] * w1;
    }
  }
#pragma unroll
  for (int m = 0; m < 4; m++) sB[m * 64 + d] = fr[m];
  __syncthreads();

  // stage B: f = fint @ sel_w[sp][l]
  float f2r[4] = {0.f, 0.f, 0.f, 0.f};
  {
    const float* W0 = sel_w + ((size_t)(sp * 4) << 12) + d;
    const float* W1 = sel_w + ((size_t)(sp * 4 + 1) << 12) + d;
#pragma unroll 8
    for (int c = 0; c < 64; c++) {
      float w0 = W0[c * 64], w1 = W1[c * 64];
      f2r[0] += sB[c] * w0;
      f2r[1] += sB[64 + c] * w1;
      f2r[2] += sB[128 + c] * w1;
      f2r[3] += sB[192 + c] * w1;
    }
  }
  float s0 = f2r[0];
  float tt = 1.0f + s0 + s0 * s0;
#pragma unroll
  for (int m = 0; m < 4; m++) sA[m * 64 + d] = f2r[m] * tt;
  __syncthreads();

  // stage C: f1 = tf @ prod_w0[sp]
  float f1r[4] = {0.f, 0.f, 0.f, 0.f};
  {
    const float* W = pw0 + ((size_t)sp << 12) + d;
#pragma unroll 8
    for (int c = 0; c < 64; c++) {
      float w = W[c * 64];
#pragma unroll
      for (int m = 0; m < 4; m++) f1r[m] += sA[m * 64 + c] * w;
    }
  }
#pragma unroll
  for (int m = 0; m < 4; m++) sB[m * 64 + d] = f1r[m];
  __syncthreads();

  // out0 = f1[:, 0] . read0
  float v = reduce64(f1r[0] * read0[d]);
  if (d == 0) out[2 * n] = v;

  // res = f1[:, 0] @ res_w[sp]; up1[n][d][0] via lu1[0]
  float u0;
  {
    const float* Wr = res_w + ((size_t)sp << 12) + d;
    const float* Wu = lu1 + d;
    float a = 0.0f, b = 0.0f;
#pragma unroll 8
    for (int c = 0; c < 64; c++) {
      float fv = sB[c];
      a += fv * Wr[c * 64];
      b += fv * Wu[c * 64];
    }
    res[((size_t)n << 6) + d] = a;
    u0 = b;
  }
  // up1[n][d][m] via lu1[1], m = 1..3; layout [n][d][4]
  {
    const float* Wu = lu1 + 4096 + d;
    float a1 = 0.f, a2 = 0.f, a3 = 0.f;
#pragma unroll 8
    for (int c = 0; c < 64; c++) {
      float w = Wu[c * 64];
      a1 += sB[64 + c] * w;
      a2 += sB[128 + c] * w;
      a3 += sB[192 + c] * w;
    }
    *(float4*)(up1 + ((size_t)n << 8) + d * 4) = make_float4(u0, a1, a2, a3);
  }
}

// ------------------------------------------------------------- node kernel 2
__global__ __launch_bounds__(64) void k_node2(const float* __restrict__ agg1,
                                              const float* __restrict__ ld1,
                                              const float* __restrict__ pw1,
                                              const float* __restrict__ res,
                                              const float* __restrict__ mlp_w1,
                                              const float* __restrict__ mlp_w2,
                                              const int* __restrict__ species,
                                              float* __restrict__ out, int N) {
  int n = blockIdx.x, d = threadIdx.x;
  int sp = species[n];
  __shared__ float sA[1024];

  const float* ag = agg1 + ((size_t)n << 10);
#pragma unroll
  for (int m = 0; m < 16; m++) sA[m * 64 + d] = ag[(m << 6) + d] * 0.0625f;
  __syncthreads();

  float g[16];
#pragma unroll
  for (int m = 0; m < 16; m++) g[m] = 0.0f;
#pragma unroll
  for (int l = 0; l < 4; l++) {
    int m0 = l * l, m1 = (l + 1) * (l + 1);
    const float* W = ld1 + l * 4096 + d;
#pragma unroll 8
    for (int c = 0; c < 64; c++) {
      float w = W[c * 64];
      for (int m = m0; m < m1; m++) g[m] += sA[m * 64 + c] * w;
    }
  }
  float inv = g[0];
#pragma unroll
  for (int m = 1; m < 16; m++) inv += g[m] * g[m];
  float qv = inv + inv * inv;
  __syncthreads();
  sA[d] = qv;
  __syncthreads();

  float a = res[((size_t)n << 6) + d];
  {
    const float* W = pw1 + ((size_t)sp << 12) + d;
#pragma unroll 8
    for (int c = 0; c < 64; c++) a += sA[c] * W[c * 64];
  }
  sA[64 + d] = a;
  __syncthreads();

  float val = 0.0f;
  if (d < 32) {
    float h = 0.0f;
#pragma unroll 8
    for (int c = 0; c < 64; c++) h += sA[64 + c] * mlp_w1[c * 32 + d];
    val = silu_f(h) * mlp_w2[d];
  }
  val = reduce64(val);
  if (d == 0) out[2 * n + 1] = val;
}

// ------------------------------------------------------------- launch
extern "C" void kernel_launch(void* const* d_in, const int* in_sizes, int n_in,
                              void* d_out, int out_size, void* d_ws, size_t ws_size,
                              hipStream_t stream) {
  const float* ev      = (const float*)d_in[0];
  const float* embed   = (const float*)d_in[1];
  const float* rw1     = (const float*)d_in[2];
  const float* rw2     = (const float*)d_in[3];
  const float* lu0     = (const float*)d_in[4];
  const float* lu1     = (const float*)d_in[5];
  const float* ld      = (const float*)d_in[6];
  const float* sel_w   = (const float*)d_in[7];
  const float* pw0     = (const float*)d_in[8];
  const float* pw1     = (const float*)d_in[9];
  const float* res_w   = (const float*)d_in[10];
  const float* read0   = (const float*)d_in[11];
  const float* mlp_w1  = (const float*)d_in[12];
  const float* mlp_w2  = (const float*)d_in[13];
  const int* species   = (const int*)d_in[14];
  const int* senders   = (const int*)d_in[15];
  const int* receivers = (const int*)d_in[16];
  float* out = (float*)d_out;

  int N = in_sizes[14];
  int E = in_sizes[15];
  int EPAD = ((E + 63) / 64) * 64;

  float* ws = (float*)d_ws;
  size_t o = 0;
  float* agg   = ws + o;  o += (size_t)N * 1024;  // interaction-2 target (16 m)
  float* agg1c = ws + o;  o += (size_t)N * 256;   // interaction-1 target (4 m)
  float* up0   = ws + o;  o += (size_t)N * 64;
  float* up1   = ws + o;  o += (size_t)N * 256;   // layout [n][d][4]
  float* resb  = ws + o;  o += (size_t)N * 64;
  _Float16* b1t  = (_Float16*)(ws + o); o += 4096;   // 128 x 64 halves
  _Float16* b2t  = (_Float16*)(ws + o); o += 12288;  // 384 x 64 halves
  _Float16* hid0 = (_Float16*)(ws + o); o += (size_t)EPAD * 32;
  _Float16* hid1 = (_Float16*)(ws + o); o += (size_t)EPAD * 32;
  float* Ysort = ws + o;  o += (size_t)EPAD * 16;
  int* row_start = (int*)(ws + o); o += (size_t)N + 1;
  int* cursor    = (int*)(ws + o); o += (size_t)N;
  int* perm      = (int*)(ws + o); o += (size_t)E;
  int* rsort     = (int*)(ws + o); o += (size_t)EPAD;
  int* ssort     = (int*)(ws + o); o += (size_t)EPAD;

  // zero both scatter targets (contiguous) and the CSR counters
  hipMemsetAsync(agg, 0, (size_t)N * 1280 * sizeof(float), stream);
  hipMemsetAsync(cursor, 0, (size_t)N * sizeof(int), stream);

  // CSR build (shared by both interactions)
  k_hist<<<(E + 255) / 256, 256, 0, stream>>>(receivers, cursor, E);
  k_scan<<<1, 256, 0, stream>>>(cursor, row_start, cursor, N);
  k_scatter<<<(E + 255) / 256, 256, 0, stream>>>(receivers, senders, cursor,
                                                 perm, rsort, ssort, E);

  k_pack<<<128, 256, 0, stream>>>(rw2, b1t, b2t);
  k_up0<<<(N + 3) / 4, 256, 0, stream>>>(embed, lu0, species, up0, N);
  k_geom<<<EPAD / 4, 256, 0, stream>>>(ev, rw1, perm, hid0, hid1, Ysort,
                                       rsort, ssort, E, EPAD);

  int fblocks = EPAD / 64;
  k_fagg1<<<fblocks, 256, 0, stream>>>(hid0, b1t, Ysort, up0, ssort, rsort,
                                       agg1c, E);
  k_node1<<<N, 64, 0, stream>>>(agg1c, ld, sel_w, pw0, res_w, lu1, read0,
                                species, out, resb, up1, N);
  k_fagg2<<<fblocks, 256, 0, stream>>>(hid1, b2t, Ysort, up1, ssort, rsort,
                                       agg, E);
  k_node2<<<N, 64, 0, stream>>>(agg, ld + 16384, pw1, resb, mlp_w1, mlp_w2,
                                species, out, N);
}

// Round 14
// 418.410 us; speedup vs baseline: 1.0295x; 1.0295x over previous
//
#include <hip/hip_runtime.h>
#include <math.h>

// MACE-like block on gfx950. CSR-sorted edge aggregation + f16 MFMA radial
// GEMM fused with message/scatter; node transforms in the measured-best R5
// access pattern.
//
// R14 = R12 (measured 417 us; R13's fagg2 column-split regressed and is
// reverted) + up1 stored in f16:
//   * fagg2's dominant cost is exposed up1-gather latency (all pipes <25%
//     busy, FETCH 80 MB). f16 halves the gather width (dwordx4->dwordx2)
//     and shrinks up1 to 5 MB (~per-XCD L2) for better hit rate.
//   * error budget: up1 multiplies f16-rounded R entries already; absmax
//     headroom is 6x.
// Sizes: N=10000 nodes, E=160000 edges, C=64, 16 sph, S=10 species.

#define WAVE_SZ 64

typedef _Float16 half8 __attribute__((ext_vector_type(8)));
typedef _Float16 half4v __attribute__((ext_vector_type(4)));
typedef float f32x4 __attribute__((ext_vector_type(4)));

__device__ __forceinline__ float silu_f(float x) { return x / (1.0f + expf(-x)); }

__device__ __forceinline__ float reduce64(float v) {
#pragma unroll
  for (int off = 32; off > 0; off >>= 1) v += __shfl_xor(v, off, WAVE_SZ);
  return v;
}

__device__ __forceinline__ void compute_Y(float x, float y, float z, float* Y) {
  float x2 = x * x, y2 = y * y, z2 = z * z;
  Y[0] = 1.0f;
  Y[1] = 1.7320508f * x;
  Y[2] = 1.7320508f * y;
  Y[3] = 1.7320508f * z;
  Y[4] = 3.8729833f * x * y;
  Y[5] = 3.8729833f * y * z;
  Y[6] = 1.118034f * (3.0f * z2 - 1.0f);
  Y[7] = 3.8729833f * x * z;
  Y[8] = 1.9364917f * (x2 - y2);
  Y[9] = 2.09165f * y * (3.0f * x2 - y2);
  Y[10] = 10.246951f * x * y * z;
  Y[11] = 1.6201852f * y * (5.0f * z2 - 1.0f);
  Y[12] = 1.3228757f * z * (5.0f * z2 - 3.0f);
  Y[13] = 1.6201852f * x * (5.0f * z2 - 1.0f);
  Y[14] = 5.1234753f * z * (x2 - y2);
  Y[15] = 2.09165f * x * (x2 - 3.0f * y2);
}

__device__ __forceinline__ void compute_rb(float r, float inv_r, float* rb) {
  float t = fminf(r * 0.2f, 1.0f);
  float t2 = t * t;
  float t5 = t2 * t2 * t;
  float env = 1.0f + t5 * (-21.0f + t * (35.0f - 15.0f * t));
  float th = 0.62831853f * r;  // pi * r / 5
  float s1 = sinf(th), c1 = cosf(th);
  float c2 = 2.0f * c1;
  float sprev = 0.0f, scur = s1;
  float coef = 0.63245553f * inv_r * env;
#pragma unroll
  for (int k = 0; k < 8; k++) {
    rb[k] = coef * scur;
    float snxt = c2 * scur - sprev;
    sprev = scur;
    scur = snxt;
  }
}

// ------------------------------------------------------------- CSR build (edges)
__global__ __launch_bounds__(256) void k_hist(const int* __restrict__ receivers,
                                              int* __restrict__ cnt, int E) {
  int e = blockIdx.x * 256 + threadIdx.x;
  if (e < E) atomicAdd(&cnt[receivers[e]], 1);
}

__global__ __launch_bounds__(256) void k_scan(const int* __restrict__ deg,
                                              int* __restrict__ row_start,
                                              int* __restrict__ cursor, int N) {
  __shared__ int part[256];
  int t = threadIdx.x;
  int K = (N + 255) / 256;
  int lo = t * K, hi = min(lo + K, N);
  int s = 0;
  for (int i = lo; i < hi; i++) s += deg[i];
  part[t] = s;
  __syncthreads();
  for (int d = 1; d < 256; d <<= 1) {
    int v = (t >= d) ? part[t - d] : 0;
    __syncthreads();
    part[t] += v;
    __syncthreads();
  }
  int run = (t == 0) ? 0 : part[t - 1];
  for (int i = lo; i < hi; i++) {
    int di = deg[i];  // deg aliases cursor; must read before overwrite
    row_start[i] = run;
    cursor[i] = run;
    run += di;
  }
  if (t == 255) row_start[N] = part[255];
}

__global__ __launch_bounds__(256) void k_scatter(const int* __restrict__ receivers,
                                                 const int* __restrict__ senders,
                                                 int* __restrict__ cursor,
                                                 int* __restrict__ perm,
                                                 int* __restrict__ rsort,
                                                 int* __restrict__ ssort, int E) {
  int e = blockIdx.x * 256 + threadIdx.x;
  if (e < E) {
    int r = receivers[e];
    int pos = atomicAdd(&cursor[r], 1);
    perm[pos] = e;
    rsort[pos] = r;
    ssort[pos] = senders[e];
  }
}

// ------------------------------------------------------------- pack rw2 -> f16 B^T
// b1t[n][k] with n = c*2+j, j in {0,1}            (128 x 64 halves)
// b2t[n][k] with n = c*6+j, cols {0,1,2,3,5,9}    (384 x 64 halves)
__global__ __launch_bounds__(256) void k_pack(const float* __restrict__ rw2,
                                              _Float16* __restrict__ b1t,
                                              _Float16* __restrict__ b2t) {
  int idx = blockIdx.x * 256 + threadIdx.x;
  if (idx < 8192) {
    int n = idx >> 6, k = idx & 63;
    int c = n >> 1, j = n & 1;
    b1t[idx] = (_Float16)rw2[k * 768 + c * 12 + j];
  } else if (idx < 32768) {
    int i2 = idx - 8192;
    int n = i2 >> 6, k = i2 & 63;
    int c = n / 6, j = n - c * 6;
    int col = (j < 4) ? j : ((j == 4) ? 5 : 9);
    b2t[i2] = (_Float16)rw2[49152 + k * 768 + c * 12 + col];
  }
}

// ------------------------------------------------------------- up0
__global__ __launch_bounds__(256) void k_up0(const float* __restrict__ embed,
                                             const float* __restrict__ lu0,
                                             const int* __restrict__ species,
                                             float* __restrict__ up0, int N) {
  int wave = threadIdx.x >> 6, lane = threadIdx.x & 63;
  int n = (blockIdx.x << 2) + wave;
  if (n >= N) return;
  int sp = species[n];
  const float* er = embed + sp * 64;
  float acc = 0.0f;
#pragma unroll 8
  for (int c = 0; c < 64; c++) acc += er[c] * lu0[c * 64 + lane];
  up0[(size_t)n * 64 + lane] = acc;
}

// ------------------------------------------------------------- geometry (sorted)
__global__ __launch_bounds__(256) void k_geom(const float* __restrict__ ev,
                                              const float* __restrict__ rw1,
                                              const int* __restrict__ perm,
                                              _Float16* __restrict__ hid0,
                                              _Float16* __restrict__ hid1,
                                              float* __restrict__ Ysort,
                                              int* __restrict__ rsort,
                                              int* __restrict__ ssort,
                                              int E, int EPAD) {
  int wave = threadIdx.x >> 6, lane = threadIdx.x & 63;
  int j = blockIdx.x * 4 + wave;
  if (j >= EPAD) return;
  if (j >= E) {
    hid0[(size_t)j * 64 + lane] = (_Float16)0.0f;
    hid1[(size_t)j * 64 + lane] = (_Float16)0.0f;
    if (lane == 0) { rsort[j] = -1; ssort[j] = 0; }
    if (lane < 16) Ysort[(size_t)j * 16 + lane] = 0.0f;
    return;
  }
  int e = perm[j];
  float vx = ev[e * 3 + 0], vy = ev[e * 3 + 1], vz = ev[e * 3 + 2];
  float r = sqrtf(vx * vx + vy * vy + vz * vz);
  float inv_r = 1.0f / (r + 1e-8f);
  float Y[16];
  compute_Y(vx * inv_r, vy * inv_r, vz * inv_r, Y);
  float rb[8];
  compute_rb(r, inv_r, rb);

  float h0 = 0.0f, h1 = 0.0f;
#pragma unroll
  for (int k = 0; k < 8; k++) {
    h0 += rb[k] * rw1[k * 64 + lane];
    h1 += rb[k] * rw1[512 + k * 64 + lane];
  }
  hid0[(size_t)j * 64 + lane] = (_Float16)silu_f(h0);
  hid1[(size_t)j * 64 + lane] = (_Float16)silu_f(h1);

  // lane m (m < 16) stores Y[m]; static selects avoid scratch spill
  float yv = Y[0];
#pragma unroll
  for (int m = 1; m < 16; m++) yv = (lane == m) ? Y[m] : yv;
  if (lane < 16) Ysort[(size_t)j * 16 + lane] = yv;
}

// ------------------------------------------------------------- fagg pass 1 (pruned)
// Only m < 4 of the aggregate is live downstream -> R cols {0,1}, 128-col
// MFMA tile, 4 accumulators, 4 atomics per receiver flush.
__global__ __launch_bounds__(256) void k_fagg1(const _Float16* __restrict__ hid,
                                               const _Float16* __restrict__ bt,
                                               const float* __restrict__ Ysort,
                                               const float* __restrict__ up0,
                                               const int* __restrict__ ssort,
                                               const int* __restrict__ rsort,
                                               float* __restrict__ agg1c, int E) {
  __shared__ _Float16 __attribute__((aligned(16))) lds[4][16 * 128];  // 16 KB
  int wave = threadIdx.x >> 6, lane = threadIdx.x & 63;
  int q = lane >> 4, mr = lane & 15;
  _Float16* L = lds[wave];
  int j0 = __builtin_amdgcn_readfirstlane((blockIdx.x * 4 + wave) * 16);

  int rs[16], ss[16];
#pragma unroll
  for (int t = 0; t < 16; t++) {
    rs[t] = rsort[j0 + t];
    ss[t] = ssort[j0 + t];
  }
  float hsv[16];
#pragma unroll
  for (int t = 0; t < 16; t++) hsv[t] = up0[((size_t)ss[t] << 6) + lane];

  const half8* Ap = (const half8*)(hid + (size_t)(j0 + mr) * 64 + q * 8);
  half8 a0 = Ap[0];
  half8 a1 = Ap[4];
  const _Float16* bp = bt + (size_t)mr * 64 + q * 8;
#pragma unroll
  for (int T = 0; T < 8; T++) {
    half8 b0 = *(const half8*)(bp + T * 1024);
    half8 b1 = *(const half8*)(bp + T * 1024 + 32);
    f32x4 acc = {0.f, 0.f, 0.f, 0.f};
    acc = __builtin_amdgcn_mfma_f32_16x16x32_f16(a0, b0, acc, 0, 0, 0);
    acc = __builtin_amdgcn_mfma_f32_16x16x32_f16(a1, b1, acc, 0, 0, 0);
#pragma unroll
    for (int r = 0; r < 4; r++)
      L[(q * 4 + r) * 128 + T * 16 + mr] = (_Float16)acc[r];
  }

  float accm[4] = {0.f, 0.f, 0.f, 0.f};
  int cur_r = (j0 < E) ? rs[0] : -1;

#pragma unroll
  for (int t = 0; t < 16; t++) {
    int j = j0 + t;
    bool ok = (j < E);
    int rr = ok ? rs[t] : -2;
    if (rr != cur_r) {  // wave-uniform branch
      if (cur_r >= 0) {
        float* base = agg1c + ((size_t)cur_r << 8) + lane;
#pragma unroll
        for (int m = 0; m < 4; m++) atomicAdd(base + (m << 6), accm[m]);
      }
#pragma unroll
      for (int m = 0; m < 4; m++) accm[m] = 0.0f;
      cur_r = rr;
    }
    if (ok) {
      float hs0 = hsv[t];
      const _Float16* Rr = L + t * 128 + lane * 2;
      float p0 = (float)Rr[0] * hs0;
      float p1 = (float)Rr[1] * hs0;
      float4 Ya = *(const float4*)(Ysort + (size_t)j * 16);  // wave-uniform
      accm[0] += p0;
      accm[1] += p1 * Ya.y;
      accm[2] += p1 * Ya.z;
      accm[3] += p1 * Ya.w;
    }
  }
  if (cur_r >= 0) {
    float* base = agg1c + ((size_t)cur_r << 8) + lane;
#pragma unroll
    for (int m = 0; m < 4; m++) atomicAdd(base + (m << 6), accm[m]);
  }
}

// ------------------------------------------------------------- fagg pass 2
// R12 structure; up1 is f16 [n][d][4] -> one dwordx2 gather per edge per lane.
__global__ __launch_bounds__(256) void k_fagg2(const _Float16* __restrict__ hid,
                                               const _Float16* __restrict__ bt,
                                               const float* __restrict__ Ysort,
                                               const _Float16* __restrict__ up1,
                                               const int* __restrict__ ssort,
                                               const int* __restrict__ rsort,
                                               float* __restrict__ agg, int E) {
  __shared__ _Float16 __attribute__((aligned(16))) lds[4][16 * 384];  // 48 KB
  int wave = threadIdx.x >> 6, lane = threadIdx.x & 63;
  int q = lane >> 4, mr = lane & 15;
  _Float16* L = lds[wave];
  int j0 = __builtin_amdgcn_readfirstlane((blockIdx.x * 4 + wave) * 16);

  int rs[16], ss[16];
#pragma unroll
  for (int t = 0; t < 16; t++) {
    rs[t] = rsort[j0 + t];
    ss[t] = ssort[j0 + t];
  }
  half4v hA[8];
#pragma unroll
  for (int t = 0; t < 8; t++)
    hA[t] = *(const half4v*)(up1 + ((size_t)ss[t] << 8) + lane * 4);

  const half8* Ap = (const half8*)(hid + (size_t)(j0 + mr) * 64 + q * 8);
  half8 a0 = Ap[0];
  half8 a1 = Ap[4];
  const _Float16* bp = bt + (size_t)mr * 64 + q * 8;
#pragma unroll
  for (int T = 0; T < 24; T++) {
    half8 b0 = *(const half8*)(bp + T * 1024);
    half8 b1 = *(const half8*)(bp + T * 1024 + 32);
    f32x4 acc = {0.f, 0.f, 0.f, 0.f};
    acc = __builtin_amdgcn_mfma_f32_16x16x32_f16(a0, b0, acc, 0, 0, 0);
    acc = __builtin_amdgcn_mfma_f32_16x16x32_f16(a1, b1, acc, 0, 0, 0);
#pragma unroll
    for (int r = 0; r < 4; r++)
      L[(q * 4 + r) * 384 + T * 16 + mr] = (_Float16)acc[r];
  }

  half4v hB[8];
#pragma unroll
  for (int t = 0; t < 8; t++)
    hB[t] = *(const half4v*)(up1 + ((size_t)ss[8 + t] << 8) + lane * 4);

  float accm[16];
#pragma unroll
  for (int m = 0; m < 16; m++) accm[m] = 0.0f;
  int cur_r = (j0 < E) ? rs[0] : -1;

#pragma unroll
  for (int t = 0; t < 16; t++) {
    int j = j0 + t;
    bool ok = (j < E);
    int rr = ok ? rs[t] : -2;
    if (rr != cur_r) {
      if (cur_r >= 0) {
        float* base = agg + ((size_t)cur_r << 10) + lane;
#pragma unroll
        for (int m = 0; m < 16; m++) atomicAdd(base + (m << 6), accm[m]);
      }
#pragma unroll
      for (int m = 0; m < 16; m++) accm[m] = 0.0f;
      cur_r = rr;
    }
    if (ok) {
      half4v hs = (t < 8) ? hA[t & 7] : hB[t & 7];
      float hs0 = (float)hs.x, hs1 = (float)hs.y;
      float hs2 = (float)hs.z, hs3 = (float)hs.w;
      const _Float16* Rr = L + t * 384 + lane * 6;
      float R0 = (float)Rr[0], R1v = (float)Rr[1];
      float R2v = (float)Rr[2], R3v = (float)Rr[3];
      float c5 = (float)Rr[4], c9 = (float)Rr[5];
      float q0 = R0 * hs0, q1 = R1v * hs0, q2 = R2v * hs0, q3 = R3v * hs0;
      const float* Yj = Ysort + (size_t)j * 16;
      float4 Ya = *(const float4*)(Yj);
      float4 Yb = *(const float4*)(Yj + 4);
      float4 Yc = *(const float4*)(Yj + 8);
      float4 Yd = *(const float4*)(Yj + 12);
      accm[0] += q0 + c9 * (hs1 * Ya.y + hs2 * Ya.z + hs3 * Ya.w);
      accm[1] += q1 * Ya.y + c5 * hs1;
      accm[2] += q1 * Ya.z + c5 * hs2;
      accm[3] += q1 * Ya.w + c5 * hs3;
      accm[4] += q2 * Yb.x;
      accm[5] += q2 * Yb.y;
      accm[6] += q2 * Yb.z;
      accm[7] += q2 * Yb.w;
      accm[8] += q2 * Yc.x;
      accm[9] += q3 * Yc.y;
      accm[10] += q3 * Yc.z;
      accm[11] += q3 * Yc.w;
      accm[12] += q3 * Yd.x;
      accm[13] += q3 * Yd.y;
      accm[14] += q3 * Yd.z;
      accm[15] += q3 * Yd.w;
    }
  }
  if (cur_r >= 0) {
    float* base = agg + ((size_t)cur_r << 10) + lane;
#pragma unroll
    for (int m = 0; m < 16; m++) atomicAdd(base + (m << 6), accm[m]);
  }
}

// ------------------------------------------------------------- node kernel 1
// R5 structure, pruned to m < 4: stage A/B use l=0 (m=0) and l=1 (m=1..3).
__global__ __launch_bounds__(64) void k_node1(const float* __restrict__ agg1c,
                                              const float* __restrict__ ld0,
                                              const float* __restrict__ sel_w,
                                              const float* __restrict__ pw0,
                                              const float* __restrict__ res_w,
                                              const float* __restrict__ lu1,
                                              const float* __restrict__ read0,
                                              const int* __restrict__ species,
                                              float* __restrict__ out,
                                              float* __restrict__ res,
                                              _Float16* __restrict__ up1, int N) {
  int n = blockIdx.x, d = threadIdx.x;
  int sp = species[n];
  __shared__ float sA[256], sB[256];

  const float* ag = agg1c + ((size_t)n << 8);
#pragma unroll
  for (int m = 0; m < 4; m++) sA[m * 64 + d] = ag[(m << 6) + d] * 0.0625f;
  __syncthreads();

  // stage A: fint = agg @ ld0[l]
  float fr[4] = {0.f, 0.f, 0.f, 0.f};
  {
    const float* W0 = ld0 + d;
    const float* W1 = ld0 + 4096 + d;
#pragma unroll 8
    for (int c = 0; c < 64; c++) {
      float w0 = W0[c * 64], w1 = W1[c * 64];
      fr[0] += sA[c] * w0;
      fr[1] += sA[64 + c] * w1;
      fr[2] += sA[128 + c] * w1;
      fr[3] += sA[192 + c] * w1;
    }
  }
#pragma unroll
  for (int m = 0; m < 4; m++) sB[m * 64 + d] = fr[m];
  __syncthreads();

  // stage B: f = fint @ sel_w[sp][l]
  float f2r[4] = {0.f, 0.f, 0.f, 0.f};
  {
    const float* W0 = sel_w + ((size_t)(sp * 4) << 12) + d;
    const float* W1 = sel_w + ((size_t)(sp * 4 + 1) << 12) + d;
#pragma unroll 8
    for (int c = 0; c < 64; c++) {
      float w0 = W0[c * 64], w1 = W1[c * 64];
      f2r[0] += sB[c] * w0;
      f2r[1] += sB[64 + c] * w1;
      f2r[2] += sB[128 + c] * w1;
      f2r[3] += sB[192 + c] * w1;
    }
  }
  float s0 = f2r[0];
  float tt = 1.0f + s0 + s0 * s0;
#pragma unroll
  for (int m = 0; m < 4; m++) sA[m * 64 + d] = f2r[m] * tt;
  __syncthreads();

  // stage C: f1 = tf @ prod_w0[sp]
  float f1r[4] = {0.f, 0.f, 0.f, 0.f};
  {
    const float* W = pw0 + ((size_t)sp << 12) + d;
#pragma unroll 8
    for (int c = 0; c < 64; c++) {
      float w = W[c * 64];
#pragma unroll
      for (int m = 0; m < 4; m++) f1r[m] += sA[m * 64 + c] * w;
    }
  }
#pragma unroll
  for (int m = 0; m < 4; m++) sB[m * 64 + d] = f1r[m];
  __syncthreads();

  // out0 = f1[:, 0] . read0
  float v = reduce64(f1r[0] * read0[d]);
  if (d == 0) out[2 * n] = v;

  // res = f1[:, 0] @ res_w[sp]; up1[n][d][0] via lu1[0]
  float u0;
  {
    const float* Wr = res_w + ((size_t)sp << 12) + d;
    const float* Wu = lu1 + d;
    float a = 0.0f, b = 0.0f;
#pragma unroll 8
    for (int c = 0; c < 64; c++) {
      float fv = sB[c];
      a += fv * Wr[c * 64];
      b += fv * Wu[c * 64];
    }
    res[((size_t)n << 6) + d] = a;
    u0 = b;
  }
  // up1[n][d][m] via lu1[1], m = 1..3; f16 layout [n][d][4]
  {
    const float* Wu = lu1 + 4096 + d;
    float a1 = 0.f, a2 = 0.f, a3 = 0.f;
#pragma unroll 8
    for (int c = 0; c < 64; c++) {
      float w = Wu[c * 64];
      a1 += sB[64 + c] * w;
      a2 += sB[128 + c] * w;
      a3 += sB[192 + c] * w;
    }
    half4v uu;
    uu.x = (_Float16)u0;
    uu.y = (_Float16)a1;
    uu.z = (_Float16)a2;
    uu.w = (_Float16)a3;
    *(half4v*)(up1 + ((size_t)n << 8) + d * 4) = uu;
  }
}

// ------------------------------------------------------------- node kernel 2
__global__ __launch_bounds__(64) void k_node2(const float* __restrict__ agg1,
                                              const float* __restrict__ ld1,
                                              const float* __restrict__ pw1,
                                              const float* __restrict__ res,
                                              const float* __restrict__ mlp_w1,
                                              const float* __restrict__ mlp_w2,
                                              const int* __restrict__ species,
                                              float* __restrict__ out, int N) {
  int n = blockIdx.x, d = threadIdx.x;
  int sp = species[n];
  __shared__ float sA[1024];

  const float* ag = agg1 + ((size_t)n << 10);
#pragma unroll
  for (int m = 0; m < 16; m++) sA[m * 64 + d] = ag[(m << 6) + d] * 0.0625f;
  __syncthreads();

  float g[16];
#pragma unroll
  for (int m = 0; m < 16; m++) g[m] = 0.0f;
#pragma unroll
  for (int l = 0; l < 4; l++) {
    int m0 = l * l, m1 = (l + 1) * (l + 1);
    const float* W = ld1 + l * 4096 + d;
#pragma unroll 8
    for (int c = 0; c < 64; c++) {
      float w = W[c * 64];
      for (int m = m0; m < m1; m++) g[m] += sA[m * 64 + c] * w;
    }
  }
  float inv = g[0];
#pragma unroll
  for (int m = 1; m < 16; m++) inv += g[m] * g[m];
  float qv = inv + inv * inv;
  __syncthreads();
  sA[d] = qv;
  __syncthreads();

  float a = res[((size_t)n << 6) + d];
  {
    const float* W = pw1 + ((size_t)sp << 12) + d;
#pragma unroll 8
    for (int c = 0; c < 64; c++) a += sA[c] * W[c * 64];
  }
  sA[64 + d] = a;
  __syncthreads();

  float val = 0.0f;
  if (d < 32) {
    float h = 0.0f;
#pragma unroll 8
    for (int c = 0; c < 64; c++) h += sA[64 + c] * mlp_w1[c * 32 + d];
    val = silu_f(h) * mlp_w2[d];
  }
  val = reduce64(val);
  if (d == 0) out[2 * n + 1] = val;
}

// ------------------------------------------------------------- launch
extern "C" void kernel_launch(void* const* d_in, const int* in_sizes, int n_in,
                              void* d_out, int out_size, void* d_ws, size_t ws_size,
                              hipStream_t stream) {
  const float* ev      = (const float*)d_in[0];
  const float* embed   = (const float*)d_in[1];
  const float* rw1     = (const float*)d_in[2];
  const float* rw2     = (const float*)d_in[3];
  const float* lu0     = (const float*)d_in[4];
  const float* lu1     = (const float*)d_in[5];
  const float* ld      = (const float*)d_in[6];
  const float* sel_w   = (const float*)d_in[7];
  const float* pw0     = (const float*)d_in[8];
  const float* pw1     = (const float*)d_in[9];
  const float* res_w   = (const float*)d_in[10];
  const float* read0   = (const float*)d_in[11];
  const float* mlp_w1  = (const float*)d_in[12];
  const float* mlp_w2  = (const float*)d_in[13];
  const int* species   = (const int*)d_in[14];
  const int* senders   = (const int*)d_in[15];
  const int* receivers = (const int*)d_in[16];
  float* out = (float*)d_out;

  int N = in_sizes[14];
  int E = in_sizes[15];
  int EPAD = ((E + 63) / 64) * 64;

  float* ws = (float*)d_ws;
  size_t o = 0;
  float* agg   = ws + o;  o += (size_t)N * 1024;  // interaction-2 target (16 m)
  float* agg1c = ws + o;  o += (size_t)N * 256;   // interaction-1 target (4 m)
  float* up0   = ws + o;  o += (size_t)N * 64;
  _Float16* up1 = (_Float16*)(ws + o); o += (size_t)N * 128;  // f16 [n][d][4]
  float* resb  = ws + o;  o += (size_t)N * 64;
  _Float16* b1t  = (_Float16*)(ws + o); o += 4096;   // 128 x 64 halves
  _Float16* b2t  = (_Float16*)(ws + o); o += 12288;  // 384 x 64 halves
  _Float16* hid0 = (_Float16*)(ws + o); o += (size_t)EPAD * 32;
  _Float16* hid1 = (_Float16*)(ws + o); o += (size_t)EPAD * 32;
  float* Ysort = ws + o;  o += (size_t)EPAD * 16;
  int* row_start = (int*)(ws + o); o += (size_t)N + 1;
  int* cursor    = (int*)(ws + o); o += (size_t)N;
  int* perm      = (int*)(ws + o); o += (size_t)E;
  int* rsort     = (int*)(ws + o); o += (size_t)EPAD;
  int* ssort     = (int*)(ws + o); o += (size_t)EPAD;

  // zero both scatter targets (contiguous) and the CSR counters
  hipMemsetAsync(agg, 0, (size_t)N * 1280 * sizeof(float), stream);
  hipMemsetAsync(cursor, 0, (size_t)N * sizeof(int), stream);

  // CSR build (shared by both interactions)
  k_hist<<<(E + 255) / 256, 256, 0, stream>>>(receivers, cursor, E);
  k_scan<<<1, 256, 0, stream>>>(cursor, row_start, cursor, N);
  k_scatter<<<(E + 255) / 256, 256, 0, stream>>>(receivers, senders, cursor,
                                                 perm, rsort, ssort, E);

  k_pack<<<128, 256, 0, stream>>>(rw2, b1t, b2t);
  k_up0<<<(N + 3) / 4, 256, 0, stream>>>(embed, lu0, species, up0, N);
  k_geom<<<EPAD / 4, 256, 0, stream>>>(ev, rw1, perm, hid0, hid1, Ysort,
                                       rsort, ssort, E, EPAD);

  int fblocks = EPAD / 64;
  k_fagg1<<<fblocks, 256, 0, stream>>>(hid0, b1t, Ysort, up0, ssort, rsort,
                                       agg1c, E);
  k_node1<<<N, 64, 0, stream>>>(agg1c, ld, sel_w, pw0, res_w, lu1, read0,
                                species, out, resb, up1, N);
  k_fagg2<<<fblocks, 256, 0, stream>>>(hid1, b2t, Ysort, up1, ssort, rsort,
                                       agg, E);
  k_node2<<<N, 64, 0, stream>>>(agg, ld + 16384, pw1, resb, mlp_w1, mlp_w2,
                                species, out, N);
}

// Round 16
// 408.568 us; speedup vs baseline: 1.0543x; 1.0241x over previous
//
#include <hip/hip_runtime.h>
#include <math.h>

// MACE-like block, gfx950. CSR-sorted edge aggregation; f16 MFMA for the
// radial GEMMs fused with message/scatter; node transforms in the
// measured-best R5 access pattern.
//
// R16 == R15 resubmitted with perturbed source hash (4th container infra
// failure; R12 established that identical logic under a new hash runs).
// Content vs R14 (418 us measured):
//   (1) k_node2 g-stage via MFMA: block = 16 nodes, 4 waves on 16-wide
//       d-tiles; per m one 16x16x64 product (2 chained 16x16x32 MFMA);
//       inv = g_0 + sum_m g_m^2 folded in C-layout registers (each lane's
//       (node,d) assignment is invariant across m). Replaces ~1216
//       ds_read_b32 per thread with 32 MFMA per wave.
//   (2) k_fagg2 __launch_bounds__(256,3): its 48 KB LDS caps occupancy at
//       3 waves/EU regardless, so allow ~170 VGPRs for load hoisting.
// Problem sizes: N=10000, E=160000, C=64, 16 sph, S=10 species.

#define LANES 64

typedef _Float16 half8 __attribute__((ext_vector_type(8)));
typedef _Float16 half4v __attribute__((ext_vector_type(4)));
typedef float f32x4 __attribute__((ext_vector_type(4)));

__device__ __forceinline__ float silu_f(float x) { return x / (1.0f + expf(-x)); }

__device__ __forceinline__ float reduce64(float v) {
#pragma unroll
  for (int off = 32; off > 0; off >>= 1) v += __shfl_xor(v, off, LANES);
  return v;
}

__device__ __forceinline__ int l_of_m(int m) {
  return (m == 0) ? 0 : ((m < 4) ? 1 : ((m < 9) ? 2 : 3));
}

__device__ __forceinline__ void compute_Y(float x, float y, float z, float* Y) {
  float x2 = x * x, y2 = y * y, z2 = z * z;
  Y[0] = 1.0f;
  Y[1] = 1.7320508f * x;
  Y[2] = 1.7320508f * y;
  Y[3] = 1.7320508f * z;
  Y[4] = 3.8729833f * x * y;
  Y[5] = 3.8729833f * y * z;
  Y[6] = 1.118034f * (3.0f * z2 - 1.0f);
  Y[7] = 3.8729833f * x * z;
  Y[8] = 1.9364917f * (x2 - y2);
  Y[9] = 2.09165f * y * (3.0f * x2 - y2);
  Y[10] = 10.246951f * x * y * z;
  Y[11] = 1.6201852f * y * (5.0f * z2 - 1.0f);
  Y[12] = 1.3228757f * z * (5.0f * z2 - 3.0f);
  Y[13] = 1.6201852f * x * (5.0f * z2 - 1.0f);
  Y[14] = 5.1234753f * z * (x2 - y2);
  Y[15] = 2.09165f * x * (x2 - 3.0f * y2);
}

__device__ __forceinline__ void compute_rb(float r, float inv_r, float* rb) {
  float t = fminf(r * 0.2f, 1.0f);
  float t2 = t * t;
  float t5 = t2 * t2 * t;
  float env = 1.0f + t5 * (-21.0f + t * (35.0f - 15.0f * t));
  float th = 0.62831853f * r;  // (pi/5) * r
  float s1 = sinf(th), c1 = cosf(th);
  float c2 = 2.0f * c1;
  float sprev = 0.0f, scur = s1;
  float coef = 0.63245553f * inv_r * env;
#pragma unroll
  for (int k = 0; k < 8; k++) {
    rb[k] = coef * scur;
    float snxt = c2 * scur - sprev;
    sprev = scur;
    scur = snxt;
  }
}

// ============================================================ CSR build
__global__ __launch_bounds__(256) void k_hist(const int* __restrict__ receivers,
                                              int* __restrict__ cnt, int E) {
  int e = blockIdx.x * 256 + threadIdx.x;
  if (e < E) atomicAdd(&cnt[receivers[e]], 1);
}

__global__ __launch_bounds__(256) void k_scan(const int* __restrict__ deg,
                                              int* __restrict__ row_start,
                                              int* __restrict__ cursor, int N) {
  __shared__ int part[256];
  int t = threadIdx.x;
  int K = (N + 255) / 256;
  int lo = t * K, hi = min(lo + K, N);
  int s = 0;
  for (int i = lo; i < hi; i++) s += deg[i];
  part[t] = s;
  __syncthreads();
  for (int d = 1; d < 256; d <<= 1) {
    int v = (t >= d) ? part[t - d] : 0;
    __syncthreads();
    part[t] += v;
    __syncthreads();
  }
  int run = (t == 0) ? 0 : part[t - 1];
  for (int i = lo; i < hi; i++) {
    int di = deg[i];  // deg aliases cursor: read before overwrite
    row_start[i] = run;
    cursor[i] = run;
    run += di;
  }
  if (t == 255) row_start[N] = part[255];
}

__global__ __launch_bounds__(256) void k_scatter(const int* __restrict__ receivers,
                                                 const int* __restrict__ senders,
                                                 int* __restrict__ cursor,
                                                 int* __restrict__ perm,
                                                 int* __restrict__ rsort,
                                                 int* __restrict__ ssort, int E) {
  int e = blockIdx.x * 256 + threadIdx.x;
  if (e < E) {
    int r = receivers[e];
    int pos = atomicAdd(&cursor[r], 1);
    perm[pos] = e;
    rsort[pos] = r;
    ssort[pos] = senders[e];
  }
}

// ============================================================ weight packing
// b1t[n][k]  n = c*2+j, j in {0,1}              (128 x 64 f16)
// b2t[n][k]  n = c*6+j, cols {0,1,2,3,5,9}      (384 x 64 f16)
// ld1t[l][d][c] = ld[1][l][c][d]                (4 x 64 x 64 f16)
__global__ __launch_bounds__(256) void k_pack(const float* __restrict__ rw2,
                                              const float* __restrict__ ldw,
                                              _Float16* __restrict__ b1t,
                                              _Float16* __restrict__ b2t,
                                              _Float16* __restrict__ ld1t) {
  int idx = blockIdx.x * 256 + threadIdx.x;
  if (idx < 8192) {
    int n = idx >> 6, k = idx & 63;
    int c = n >> 1, j = n & 1;
    b1t[idx] = (_Float16)rw2[k * 768 + c * 12 + j];
  } else if (idx < 32768) {
    int i2 = idx - 8192;
    int n = i2 >> 6, k = i2 & 63;
    int c = n / 6, j = n - c * 6;
    int col = (j < 4) ? j : ((j == 4) ? 5 : 9);
    b2t[i2] = (_Float16)rw2[49152 + k * 768 + c * 12 + col];
  } else if (idx < 49152) {
    int i3 = idx - 32768;
    int l = i3 >> 12;
    int rem = i3 & 4095;
    int dd = rem >> 6, cc = rem & 63;
    ld1t[i3] = (_Float16)ldw[16384 + (l << 12) + (cc << 6) + dd];
  }
}

// ============================================================ up0
__global__ __launch_bounds__(256) void k_up0(const float* __restrict__ embed,
                                             const float* __restrict__ lu0,
                                             const int* __restrict__ species,
                                             float* __restrict__ up0, int N) {
  int wave = threadIdx.x >> 6, lane = threadIdx.x & 63;
  int n = (blockIdx.x << 2) + wave;
  if (n >= N) return;
  int sp = species[n];
  const float* er = embed + sp * 64;
  float acc = 0.0f;
#pragma unroll 8
  for (int c = 0; c < 64; c++) acc += er[c] * lu0[c * 64 + lane];
  up0[(size_t)n * 64 + lane] = acc;
}

// ============================================================ geometry
__global__ __launch_bounds__(256) void k_geom(const float* __restrict__ ev,
                                              const float* __restrict__ rw1,
                                              const int* __restrict__ perm,
                                              _Float16* __restrict__ hid0,
                                              _Float16* __restrict__ hid1,
                                              float* __restrict__ Ysort,
                                              int* __restrict__ rsort,
                                              int* __restrict__ ssort,
                                              int E, int EPAD) {
  int wave = threadIdx.x >> 6, lane = threadIdx.x & 63;
  int j = blockIdx.x * 4 + wave;
  if (j >= EPAD) return;
  if (j >= E) {
    hid0[(size_t)j * 64 + lane] = (_Float16)0.0f;
    hid1[(size_t)j * 64 + lane] = (_Float16)0.0f;
    if (lane == 0) { rsort[j] = -1; ssort[j] = 0; }
    if (lane < 16) Ysort[(size_t)j * 16 + lane] = 0.0f;
    return;
  }
  int e = perm[j];
  float vx = ev[e * 3 + 0], vy = ev[e * 3 + 1], vz = ev[e * 3 + 2];
  float r = sqrtf(vx * vx + vy * vy + vz * vz);
  float inv_r = 1.0f / (r + 1e-8f);
  float Y[16];
  compute_Y(vx * inv_r, vy * inv_r, vz * inv_r, Y);
  float rb[8];
  compute_rb(r, inv_r, rb);

  float h0 = 0.0f, h1 = 0.0f;
#pragma unroll
  for (int k = 0; k < 8; k++) {
    h0 += rb[k] * rw1[k * 64 + lane];
    h1 += rb[k] * rw1[512 + k * 64 + lane];
  }
  hid0[(size_t)j * 64 + lane] = (_Float16)silu_f(h0);
  hid1[(size_t)j * 64 + lane] = (_Float16)silu_f(h1);

  // lane m (m < 16) keeps Y[m]; static selects, no scratch
  float yv = Y[0];
#pragma unroll
  for (int m = 1; m < 16; m++) yv = (lane == m) ? Y[m] : yv;
  if (lane < 16) Ysort[(size_t)j * 16 + lane] = yv;
}

// ============================================================ fagg pass 1
// Pruned: only m<4 live downstream -> R cols {0,1}; 128-col MFMA tile.
__global__ __launch_bounds__(256) void k_fagg1(const _Float16* __restrict__ hid,
                                               const _Float16* __restrict__ bt,
                                               const float* __restrict__ Ysort,
                                               const float* __restrict__ up0,
                                               const int* __restrict__ ssort,
                                               const int* __restrict__ rsort,
                                               float* __restrict__ agg1c, int E) {
  __shared__ _Float16 __attribute__((aligned(16))) lds[4][16 * 128];  // 16 KB
  int wave = threadIdx.x >> 6, lane = threadIdx.x & 63;
  int q = lane >> 4, mr = lane & 15;
  _Float16* L = lds[wave];
  int j0 = __builtin_amdgcn_readfirstlane((blockIdx.x * 4 + wave) * 16);

  int rs[16], ss[16];
#pragma unroll
  for (int t = 0; t < 16; t++) {
    rs[t] = rsort[j0 + t];
    ss[t] = ssort[j0 + t];
  }
  float hsv[16];
#pragma unroll
  for (int t = 0; t < 16; t++) hsv[t] = up0[((size_t)ss[t] << 6) + lane];

  const half8* Ap = (const half8*)(hid + (size_t)(j0 + mr) * 64 + q * 8);
  half8 a0 = Ap[0];
  half8 a1 = Ap[4];
  const _Float16* bp = bt + (size_t)mr * 64 + q * 8;
#pragma unroll
  for (int T = 0; T < 8; T++) {
    half8 b0 = *(const half8*)(bp + T * 1024);
    half8 b1 = *(const half8*)(bp + T * 1024 + 32);
    f32x4 acc = {0.f, 0.f, 0.f, 0.f};
    acc = __builtin_amdgcn_mfma_f32_16x16x32_f16(a0, b0, acc, 0, 0, 0);
    acc = __builtin_amdgcn_mfma_f32_16x16x32_f16(a1, b1, acc, 0, 0, 0);
#pragma unroll
    for (int r = 0; r < 4; r++)
      L[(q * 4 + r) * 128 + T * 16 + mr] = (_Float16)acc[r];
  }

  float accm[4] = {0.f, 0.f, 0.f, 0.f};
  int cur_r = (j0 < E) ? rs[0] : -1;

#pragma unroll
  for (int t = 0; t < 16; t++) {
    int j = j0 + t;
    bool ok = (j < E);
    int rr = ok ? rs[t] : -2;
    if (rr != cur_r) {  // wave-uniform
      if (cur_r >= 0) {
        float* base = agg1c + ((size_t)cur_r << 8) + lane;
#pragma unroll
        for (int m = 0; m < 4; m++) atomicAdd(base + (m << 6), accm[m]);
      }
#pragma unroll
      for (int m = 0; m < 4; m++) accm[m] = 0.0f;
      cur_r = rr;
    }
    if (ok) {
      float hs0 = hsv[t];
      const _Float16* Rr = L + t * 128 + lane * 2;
      float p0 = (float)Rr[0] * hs0;
      float p1 = (float)Rr[1] * hs0;
      float4 Ya = *(const float4*)(Ysort + (size_t)j * 16);  // wave-uniform
      accm[0] += p0;
      accm[1] += p1 * Ya.y;
      accm[2] += p1 * Ya.z;
      accm[3] += p1 * Ya.w;
    }
  }
  if (cur_r >= 0) {
    float* base = agg1c + ((size_t)cur_r << 8) + lane;
#pragma unroll
    for (int m = 0; m < 4; m++) atomicAdd(base + (m << 6), accm[m]);
  }
}

// ============================================================ fagg pass 2
// R12 structure; up1 f16; (256,3) bounds since 48 KB LDS caps occupancy.
__global__ __launch_bounds__(256, 3) void k_fagg2(const _Float16* __restrict__ hid,
                                                  const _Float16* __restrict__ bt,
                                                  const float* __restrict__ Ysort,
                                                  const _Float16* __restrict__ up1,
                                                  const int* __restrict__ ssort,
                                                  const int* __restrict__ rsort,
                                                  float* __restrict__ agg, int E) {
  __shared__ _Float16 __attribute__((aligned(16))) lds[4][16 * 384];  // 48 KB
  int wave = threadIdx.x >> 6, lane = threadIdx.x & 63;
  int q = lane >> 4, mr = lane & 15;
  _Float16* L = lds[wave];
  int j0 = __builtin_amdgcn_readfirstlane((blockIdx.x * 4 + wave) * 16);

  int rs[16], ss[16];
#pragma unroll
  for (int t = 0; t < 16; t++) {
    rs[t] = rsort[j0 + t];
    ss[t] = ssort[j0 + t];
  }
  half4v hA[8];
#pragma unroll
  for (int t = 0; t < 8; t++)
    hA[t] = *(const half4v*)(up1 + ((size_t)ss[t] << 8) + lane * 4);

  const half8* Ap = (const half8*)(hid + (size_t)(j0 + mr) * 64 + q * 8);
  half8 a0 = Ap[0];
  half8 a1 = Ap[4];
  const _Float16* bp = bt + (size_t)mr * 64 + q * 8;
#pragma unroll
  for (int T = 0; T < 24; T++) {
    half8 b0 = *(const half8*)(bp + T * 1024);
    half8 b1 = *(const half8*)(bp + T * 1024 + 32);
    f32x4 acc = {0.f, 0.f, 0.f, 0.f};
    acc = __builtin_amdgcn_mfma_f32_16x16x32_f16(a0, b0, acc, 0, 0, 0);
    acc = __builtin_amdgcn_mfma_f32_16x16x32_f16(a1, b1, acc, 0, 0, 0);
#pragma unroll
    for (int r = 0; r < 4; r++)
      L[(q * 4 + r) * 384 + T * 16 + mr] = (_Float16)acc[r];
  }

  half4v hB[8];
#pragma unroll
  for (int t = 0; t < 8; t++)
    hB[t] = *(const half4v*)(up1 + ((size_t)ss[8 + t] << 8) + lane * 4);

  float accm[16];
#pragma unroll
  for (int m = 0; m < 16; m++) accm[m] = 0.0f;
  int cur_r = (j0 < E) ? rs[0] : -1;

#pragma unroll
  for (int t = 0; t < 16; t++) {
    int j = j0 + t;
    bool ok = (j < E);
    int rr = ok ? rs[t] : -2;
    if (rr != cur_r) {
      if (cur_r >= 0) {
        float* base = agg + ((size_t)cur_r << 10) + lane;
#pragma unroll
        for (int m = 0; m < 16; m++) atomicAdd(base + (m << 6), accm[m]);
      }
#pragma unroll
      for (int m = 0; m < 16; m++) accm[m] = 0.0f;
      cur_r = rr;
    }
    if (ok) {
      half4v hs = (t < 8) ? hA[t & 7] : hB[t & 7];
      float hs0 = (float)hs.x, hs1 = (float)hs.y;
      float hs2 = (float)hs.z, hs3 = (float)hs.w;
      const _Float16* Rr = L + t * 384 + lane * 6;
      float R0 = (float)Rr[0], R1v = (float)Rr[1];
      float R2v = (float)Rr[2], R3v = (float)Rr[3];
      float c5 = (float)Rr[4], c9 = (float)Rr[5];
      float q0 = R0 * hs0, q1 = R1v * hs0, q2 = R2v * hs0, q3 = R3v * hs0;
      const float* Yj = Ysort + (size_t)j * 16;
      float4 Ya = *(const float4*)(Yj);
      float4 Yb = *(const float4*)(Yj + 4);
      float4 Yc = *(const float4*)(Yj + 8);
      float4 Yd = *(const float4*)(Yj + 12);
      accm[0] += q0 + c9 * (hs1 * Ya.y + hs2 * Ya.z + hs3 * Ya.w);
      accm[1] += q1 * Ya.y + c5 * hs1;
      accm[2] += q1 * Ya.z + c5 * hs2;
      accm[3] += q1 * Ya.w + c5 * hs3;
      accm[4] += q2 * Yb.x;
      accm[5] += q2 * Yb.y;
      accm[6] += q2 * Yb.z;
      accm[7] += q2 * Yb.w;
      accm[8] += q2 * Yc.x;
      accm[9] += q3 * Yc.y;
      accm[10] += q3 * Yc.z;
      accm[11] += q3 * Yc.w;
      accm[12] += q3 * Yd.x;
      accm[13] += q3 * Yd.y;
      accm[14] += q3 * Yd.z;
      accm[15] += q3 * Yd.w;
    }
  }
  if (cur_r >= 0) {
    float* base = agg + ((size_t)cur_r << 10) + lane;
#pragma unroll
    for (int m = 0; m < 16; m++) atomicAdd(base + (m << 6), accm[m]);
  }
}

// ============================================================ node kernel 1
// R5 structure, m<4 pruned: stage A/B use l=0 (m=0) and l=1 (m=1..3).
__global__ __launch_bounds__(64) void k_node1(const float* __restrict__ agg1c,
                                              const float* __restrict__ ld0,
                                              const float* __restrict__ sel_w,
                                              const float* __restrict__ pw0,
                                              const float* __restrict__ res_w,
                                              const float* __restrict__ lu1,
                                              const float* __restrict__ read0,
                                              const int* __restrict__ species,
                                              float* __restrict__ out,
                                              float* __restrict__ res,
                                              _Float16* __restrict__ up1, int N) {
  int n = blockIdx.x, d = threadIdx.x;
  int sp = species[n];
  __shared__ float sA[256], sB[256];

  const float* ag = agg1c + ((size_t)n << 8);
#pragma unroll
  for (int m = 0; m < 4; m++) sA[m * 64 + d] = ag[(m << 6) + d] * 0.0625f;
  __syncthreads();

  // A: fint = agg @ ld0[l]
  float fr[4] = {0.f, 0.f, 0.f, 0.f};
  {
    const float* W0 = ld0 + d;
    const float* W1 = ld0 + 4096 + d;
#pragma unroll 8
    for (int c = 0; c < 64; c++) {
      float w0 = W0[c * 64], w1 = W1[c * 64];
      fr[0] += sA[c] * w0;
      fr[1] += sA[64 + c] * w1;
      fr[2] += sA[128 + c] * w1;
      fr[3] += sA[192 + c] * w1;
    }
  }
#pragma unroll
  for (int m = 0; m < 4; m++) sB[m * 64 + d] = fr[m];
  __syncthreads();

  // B: f = fint @ sel_w[sp][l]
  float f2r[4] = {0.f, 0.f, 0.f, 0.f};
  {
    const float* W0 = sel_w + ((size_t)(sp * 4) << 12) + d;
    const float* W1 = sel_w + ((size_t)(sp * 4 + 1) << 12) + d;
#pragma unroll 8
    for (int c = 0; c < 64; c++) {
      float w0 = W0[c * 64], w1 = W1[c * 64];
      f2r[0] += sB[c] * w0;
      f2r[1] += sB[64 + c] * w1;
      f2r[2] += sB[128 + c] * w1;
      f2r[3] += sB[192 + c] * w1;
    }
  }
  float s0 = f2r[0];
  float tt = 1.0f + s0 + s0 * s0;
#pragma unroll
  for (int m = 0; m < 4; m++) sA[m * 64 + d] = f2r[m] * tt;
  __syncthreads();

  // C: f1 = tf @ prod_w0[sp]
  float f1r[4] = {0.f, 0.f, 0.f, 0.f};
  {
    const float* W = pw0 + ((size_t)sp << 12) + d;
#pragma unroll 8
    for (int c = 0; c < 64; c++) {
      float w = W[c * 64];
#pragma unroll
      for (int m = 0; m < 4; m++) f1r[m] += sA[m * 64 + c] * w;
    }
  }
#pragma unroll
  for (int m = 0; m < 4; m++) sB[m * 64 + d] = f1r[m];
  __syncthreads();

  // out0 = f1[:,0] . read0
  float v = reduce64(f1r[0] * read0[d]);
  if (d == 0) out[2 * n] = v;

  // res = f1[:,0] @ res_w[sp]; up1 channel 0 via lu1[0]
  float u0;
  {
    const float* Wr = res_w + ((size_t)sp << 12) + d;
    const float* Wu = lu1 + d;
    float a = 0.0f, b = 0.0f;
#pragma unroll 8
    for (int c = 0; c < 64; c++) {
      float fv = sB[c];
      a += fv * Wr[c * 64];
      b += fv * Wu[c * 64];
    }
    res[((size_t)n << 6) + d] = a;
    u0 = b;
  }
  // up1 channels 1..3 via lu1[1]; f16 layout [n][d][4]
  {
    const float* Wu = lu1 + 4096 + d;
    float a1 = 0.f, a2 = 0.f, a3 = 0.f;
#pragma unroll 8
    for (int c = 0; c < 64; c++) {
      float w = Wu[c * 64];
      a1 += sB[64 + c] * w;
      a2 += sB[128 + c] * w;
      a3 += sB[192 + c] * w;
    }
    half4v uu;
    uu.x = (_Float16)u0;
    uu.y = (_Float16)a1;
    uu.z = (_Float16)a2;
    uu.w = (_Float16)a3;
    *(half4v*)(up1 + ((size_t)n << 8) + d * 4) = uu;
  }
}

// ============================================================ node kernel 2
// MFMA g-stage: block = 16 nodes, 4 waves on 16-wide d-tiles; per m one
// 16x16x64 product; inv folded in C-layout registers.
__global__ __launch_bounds__(256) void k_node2(const float* __restrict__ agg1,
                                               const _Float16* __restrict__ ld1t,
                                               const float* __restrict__ pw1,
                                               const float* __restrict__ res,
                                               const float* __restrict__ mlp_w1,
                                               const float* __restrict__ mlp_w2,
                                               const int* __restrict__ species,
                                               float* __restrict__ out, int N) {
  __shared__ float sq[16 * 65];
  __shared__ float sf[16 * 65];
  int tid = threadIdx.x;
  int wave = tid >> 6, lane = tid & 63;
  int q = lane >> 4, mr = lane & 15;
  int nb = blockIdx.x * 16;

  int arow = min(nb + mr, N - 1);
  const float* Arow = agg1 + ((size_t)arow << 10);  // [m][c] of node arow

  float inv[4] = {0.f, 0.f, 0.f, 0.f};
#pragma unroll
  for (int m = 0; m < 16; m++) {
    int l = l_of_m(m);
    const float* ap = Arow + (m << 6) + q * 8;
    half8 a0, a1;
#pragma unroll
    for (int i = 0; i < 8; i++) {
      a0[i] = (_Float16)(ap[i] * 0.0625f);
      a1[i] = (_Float16)(ap[32 + i] * 0.0625f);
    }
    const _Float16* bp = ld1t + (l << 12) + ((wave * 16 + mr) << 6) + q * 8;
    half8 b0 = *(const half8*)(bp);
    half8 b1 = *(const half8*)(bp + 32);
    f32x4 acc = {0.f, 0.f, 0.f, 0.f};
    acc = __builtin_amdgcn_mfma_f32_16x16x32_f16(a0, b0, acc, 0, 0, 0);
    acc = __builtin_amdgcn_mfma_f32_16x16x32_f16(a1, b1, acc, 0, 0, 0);
    if (m == 0) {
#pragma unroll
      for (int r = 0; r < 4; r++) inv[r] += acc[r];
    } else {
#pragma unroll
      for (int r = 0; r < 4; r++) inv[r] += acc[r] * acc[r];
    }
  }
#pragma unroll
  for (int r = 0; r < 4; r++) {
    float iv = inv[r];
    sq[(q * 4 + r) * 65 + wave * 16 + mr] = iv + iv * iv;
  }
  __syncthreads();

  // f2 = res + qv @ pw1[sp]; thread handles 4 local nodes at column d
  int d = lane;
#pragma unroll
  for (int g = 0; g < 4; g++) {
    int nl = wave + 4 * g;  // 0..15
    int n = nb + nl;
    int nc = min(n, N - 1);
    int sp = species[nc];
    float a = res[((size_t)nc << 6) + d];
    const float* W = pw1 + ((size_t)sp << 12) + d;
#pragma unroll 8
    for (int c = 0; c < 64; c++) a += sq[nl * 65 + c] * W[c * 64];
    sf[nl * 65 + d] = a;
  }
  __syncthreads();

  // MLP tail: 32-lane half-wave per node, lane = hidden unit
#pragma unroll
  for (int p = 0; p < 2; p++) {
    int nl = wave * 2 + (lane >> 5) + p * 8;
    int n = nb + nl;
    int h = lane & 31;
    float hh = 0.f;
#pragma unroll 8
    for (int c = 0; c < 64; c++) hh += sf[nl * 65 + c] * mlp_w1[c * 32 + h];
    float val = silu_f(hh) * mlp_w2[h];
#pragma unroll
    for (int off = 16; off > 0; off >>= 1) val += __shfl_xor(val, off, 64);
    if (h == 0 && n < N) out[2 * n + 1] = val;
  }
}

// ============================================================ launch
extern "C" void kernel_launch(void* const* d_in, const int* in_sizes, int n_in,
                              void* d_out, int out_size, void* d_ws, size_t ws_size,
                              hipStream_t stream) {
  const float* ev      = (const float*)d_in[0];
  const float* embed   = (const float*)d_in[1];
  const float* rw1     = (const float*)d_in[2];
  const float* rw2     = (const float*)d_in[3];
  const float* lu0     = (const float*)d_in[4];
  const float* lu1     = (const float*)d_in[5];
  const float* ld      = (const float*)d_in[6];
  const float* sel_w   = (const float*)d_in[7];
  const float* pw0     = (const float*)d_in[8];
  const float* pw1     = (const float*)d_in[9];
  const float* res_w   = (const float*)d_in[10];
  const float* read0   = (const float*)d_in[11];
  const float* mlp_w1  = (const float*)d_in[12];
  const float* mlp_w2  = (const float*)d_in[13];
  const int* species   = (const int*)d_in[14];
  const int* senders   = (const int*)d_in[15];
  const int* receivers = (const int*)d_in[16];
  float* out = (float*)d_out;

  int N = in_sizes[14];
  int E = in_sizes[15];
  int EPAD = ((E + 63) / 64) * 64;

  float* ws = (float*)d_ws;
  size_t o = 0;
  float* agg   = ws + o;  o += (size_t)N * 1024;  // interaction-2 target
  float* agg1c = ws + o;  o += (size_t)N * 256;   // interaction-1 target (m<4)
  float* up0   = ws + o;  o += (size_t)N * 64;
  _Float16* up1 = (_Float16*)(ws + o); o += (size_t)N * 128;  // f16 [n][d][4]
  float* resb  = ws + o;  o += (size_t)N * 64;
  _Float16* b1t  = (_Float16*)(ws + o); o += 4096;   // 128 x 64 f16
  _Float16* b2t  = (_Float16*)(ws + o); o += 12288;  // 384 x 64 f16
  _Float16* ld1t = (_Float16*)(ws + o); o += 8192;   // 4 x 64 x 64 f16
  _Float16* hid0 = (_Float16*)(ws + o); o += (size_t)EPAD * 32;
  _Float16* hid1 = (_Float16*)(ws + o); o += (size_t)EPAD * 32;
  float* Ysort = ws + o;  o += (size_t)EPAD * 16;
  int* row_start = (int*)(ws + o); o += (size_t)N + 1;
  int* cursor    = (int*)(ws + o); o += (size_t)N;
  int* perm      = (int*)(ws + o); o += (size_t)E;
  int* rsort     = (int*)(ws + o); o += (size_t)EPAD;
  int* ssort     = (int*)(ws + o); o += (size_t)EPAD;

  hipMemsetAsync(agg, 0, (size_t)N * 1280 * sizeof(float), stream);
  hipMemsetAsync(cursor, 0, (size_t)N * sizeof(int), stream);

  k_hist<<<(E + 255) / 256, 256, 0, stream>>>(receivers, cursor, E);
  k_scan<<<1, 256, 0, stream>>>(cursor, row_start, cursor, N);
  k_scatter<<<(E + 255) / 256, 256, 0, stream>>>(receivers, senders, cursor,
                                                 perm, rsort, ssort, E);

  k_pack<<<192, 256, 0, stream>>>(rw2, ld, b1t, b2t, ld1t);
  k_up0<<<(N + 3) / 4, 256, 0, stream>>>(embed, lu0, species, up0, N);
  k_geom<<<EPAD / 4, 256, 0, stream>>>(ev, rw1, perm, hid0, hid1, Ysort,
                                       rsort, ssort, E, EPAD);

  int fblocks = EPAD / 64;
  k_fagg1<<<fblocks, 256, 0, stream>>>(hid0, b1t, Ysort, up0, ssort, rsort,
                                       agg1c, E);
  k_node1<<<N, 64, 0, stream>>>(agg1c, ld, sel_w, pw0, res_w, lu1, read0,
                                species, out, resb, up1, N);
  k_fagg2<<<fblocks, 256, 0, stream>>>(hid1, b2t, Ysort, up1, ssort, rsort,
                                       agg, E);
  k_node2<<<(N + 15) / 16, 256, 0, stream>>>(agg, ld1t, pw1, resb, mlp_w1,
                                             mlp_w2, species, out, N);
}